// Round 5
// baseline (246.803 us; speedup 1.0000x reference)
//
#include <hip/hip_runtime.h>
#include <math.h>

#define NHOP 2
#define MEM 32
#define DIM 64

typedef __attribute__((ext_vector_type(8))) short short8v;
typedef __attribute__((ext_vector_type(4))) float f32x4;

__device__ __forceinline__ float fast_tanh(float x) {
    const float e = __expf(2.f * x);
    return 1.f - 2.f / (e + 1.f);
}

// round-to-nearest-even fp32 -> bf16 bits
__device__ __forceinline__ short bf16b(float x) {
    union { float f; unsigned u; } c; c.f = x;
    const unsigned r = c.u + 0x7fffu + ((c.u >> 16) & 1u);
    return (short)(r >> 16);
}

// ---------------- Kernel A: pure stream ----------------
// Rh[idx][d] = sum_e R[idx][d][e] * h[idx][e],  idx = (b*NHOP+hop)*MEM+m
// Line-exact: every fetched 64B line fully consumed within one instruction.
// Grid: one block = 16 matvecs (256 KB); wave wv handles matvecs wv*4..wv*4+3.
__global__ __launch_bounds__(256) void rh_stream(
    const float* __restrict__ Rs,
    const float* __restrict__ hs,
    float* __restrict__ rh)
{
    const int tid = threadIdx.x;
    const int l  = tid & 63, wv = tid >> 6;
    const int e0 = l & 3,  dq = l >> 2;
    const int mv0 = blockIdx.x * 16 + wv * 4;

    #pragma unroll 2
    for (int j = 0; j < 4; ++j) {
        const int idx = mv0 + j;
        const float* __restrict__ Rm = Rs + (size_t)idx * (DIM * DIM);
        const float* __restrict__ hm = hs + (size_t)idx * DIM;
        const float4 hv0 = *reinterpret_cast<const float4*>(hm + 4 * e0);
        const float4 hv1 = *reinterpret_cast<const float4*>(hm + 4 * e0 + 16);
        const float4 hv2 = *reinterpret_cast<const float4*>(hm + 4 * e0 + 32);
        const float4 hv3 = *reinterpret_cast<const float4*>(hm + 4 * e0 + 48);
        float p[4];
        #pragma unroll
        for (int dblk = 0; dblk < 4; ++dblk) {
            const int d = 4 * dq + dblk;           // lane dq ends with d = 4dq..4dq+3
            const float* __restrict__ row = Rm + d * DIM + 4 * e0;
            const float4 r0 = *reinterpret_cast<const float4*>(row);
            const float4 r1 = *reinterpret_cast<const float4*>(row + 16);
            const float4 r2 = *reinterpret_cast<const float4*>(row + 32);
            const float4 r3 = *reinterpret_cast<const float4*>(row + 48);
            float s = r0.x*hv0.x + r0.y*hv0.y + r0.z*hv0.z + r0.w*hv0.w;
            s = fmaf(r1.x, hv1.x, fmaf(r1.y, hv1.y, fmaf(r1.z, hv1.z, fmaf(r1.w, hv1.w, s))));
            s = fmaf(r2.x, hv2.x, fmaf(r2.y, hv2.y, fmaf(r2.z, hv2.z, fmaf(r2.w, hv2.w, s))));
            s = fmaf(r3.x, hv3.x, fmaf(r3.y, hv3.y, fmaf(r3.z, hv3.z, fmaf(r3.w, hv3.w, s))));
            s += __shfl_xor(s, 1);
            s += __shfl_xor(s, 2);
            p[dblk] = s;
        }
        if (e0 == 0) {
            const float4 v = make_float4(p[0], p[1], p[2], p[3]);
            *reinterpret_cast<float4*>(rh + (size_t)idx * DIM + 4 * dq) = v;  // 256B/matvec
        }
    }
}

// ---------------- Kernel B: per-batch chain ----------------
__global__ __launch_bounds__(256) void ripple_chain(
    const float* __restrict__ rh,     // (B,2,32,64) from ws
    const float* __restrict__ ts,     // (B,2,32,64)
    const float* __restrict__ vs,     // (B,64)
    const float* __restrict__ W1_w,   // (64,256)
    const float* __restrict__ W1_b,   // (64)
    const float* __restrict__ W2_w,   // (1,64)
    const float* __restrict__ Wmem_w, // (2,64,192)
    const float* __restrict__ Wmem_b, // (2,64)
    const float* __restrict__ z_w,    // (64,128)
    const float* __restrict__ z_b,    // (64)
    float* __restrict__ out)          // (B)
{
    __shared__ float Rh_sm[NHOP][MEM][68];   // stride 68: P2 reads ~2-way conflict only
    __shared__ float M_sm[DIM], o_sm[DIM], onew_sm[DIM], vs_sm[DIM];
    __shared__ float Zp[2][MEM];

    const int b   = blockIdx.x;
    const int tid = threadIdx.x;
    const int l   = tid & 63;
    const int wv  = tid >> 6;

    // Stage Rh (16 KB) from ws; layout row = hop*32+m (stride 68 in LDS).
    {
        const float* __restrict__ src = rh + (size_t)b * (NHOP * MEM * DIM);
        #pragma unroll
        for (int it = 0; it < 4; ++it) {
            const int s   = it * 1024 + tid * 4;
            const int row = s >> 6, col = s & 63;
            *reinterpret_cast<float4*>(&Rh_sm[0][0][0] + row * 68 + col) =
                *reinterpret_cast<const float4*>(src + s);
        }
    }
    if (tid < DIM) {
        const float v = vs[b * DIM + tid];
        M_sm[tid] = v; o_sm[tid] = v; vs_sm[tid] = v;
    }

    // Preload W1 B-frags straight global->regs (hop-invariant, L2-hot).
    // Convention (shared with A-gen): frag (kt,nt): lane ll holds
    // f = kt*32 + (ll>>4)*8 + p, n = nt*16 + (ll&15), p = 0..7.
    const int g   = l >> 4;
    const int col = l & 15;
    const int mt  = wv & 1;
    const int nh  = wv >> 1;
    short8v wfrag[8][2];
    #pragma unroll
    for (int kt = 0; kt < 8; ++kt) {
        #pragma unroll
        for (int q = 0; q < 2; ++q) {
            const int n  = (nh * 2 + q) * 16 + col;
            const int f0 = kt * 32 + g * 8;
            const float4 wa = *reinterpret_cast<const float4*>(W1_w + n * 256 + f0);
            const float4 wb = *reinterpret_cast<const float4*>(W1_w + n * 256 + f0 + 4);
            short8v v;
            v[0] = bf16b(wa.x); v[1] = bf16b(wa.y); v[2] = bf16b(wa.z); v[3] = bf16b(wa.w);
            v[4] = bf16b(wb.x); v[5] = bf16b(wb.y); v[6] = bf16b(wb.z); v[7] = bf16b(wb.w);
            wfrag[kt][q] = v;
        }
    }
    const int n0 = (nh * 2 + 0) * 16 + col;
    const int n1 = (nh * 2 + 1) * 16 + col;
    const float b1a = W1_b[n0], b1b = W1_b[n1];
    const float w2a = W2_w[n0], w2b = W2_w[n1];
    __syncthreads();   // bar1: Rh_sm + M/o/vs ready

    for (int hop = 0; hop < NHOP; ++hop) {
        const float* __restrict__ tbase = ts + (size_t)(b * NHOP + hop) * MEM * DIM;

        // ---- P2 (MFMA): preact = z @ W1T ; Z = W2 . tanh(preact + b1) ----
        {
            const int m = mt * 16 + col;
            f32x4 acc0 = {0.f, 0.f, 0.f, 0.f};
            f32x4 acc1 = {0.f, 0.f, 0.f, 0.f};
            #pragma unroll
            for (int kt = 0; kt < 8; ++kt) {
                const int part = kt >> 1;              // 0:Rh*o 1:Rh*M 2:|Rh-o| 3:|Rh-M|
                const int e0 = (kt & 1) * 32 + g * 8;
                const float4 r0 = *reinterpret_cast<const float4*>(&Rh_sm[hop][m][e0]);
                const float4 r1 = *reinterpret_cast<const float4*>(&Rh_sm[hop][m][e0 + 4]);
                const float* vsrc = (part & 1) ? M_sm : o_sm;
                const float4 q0 = *reinterpret_cast<const float4*>(vsrc + e0);
                const float4 q1 = *reinterpret_cast<const float4*>(vsrc + e0 + 4);
                float zz[8];
                if (part < 2) {
                    zz[0] = r0.x*q0.x; zz[1] = r0.y*q0.y; zz[2] = r0.z*q0.z; zz[3] = r0.w*q0.w;
                    zz[4] = r1.x*q1.x; zz[5] = r1.y*q1.y; zz[6] = r1.z*q1.z; zz[7] = r1.w*q1.w;
                } else {
                    zz[0] = fabsf(r0.x-q0.x); zz[1] = fabsf(r0.y-q0.y);
                    zz[2] = fabsf(r0.z-q0.z); zz[3] = fabsf(r0.w-q0.w);
                    zz[4] = fabsf(r1.x-q1.x); zz[5] = fabsf(r1.y-q1.y);
                    zz[6] = fabsf(r1.z-q1.z); zz[7] = fabsf(r1.w-q1.w);
                }
                short8v a;
                a[0] = bf16b(zz[0]); a[1] = bf16b(zz[1]); a[2] = bf16b(zz[2]); a[3] = bf16b(zz[3]);
                a[4] = bf16b(zz[4]); a[5] = bf16b(zz[5]); a[6] = bf16b(zz[6]); a[7] = bf16b(zz[7]);
                acc0 = __builtin_amdgcn_mfma_f32_16x16x32_bf16(a, wfrag[kt][0], acc0, 0, 0, 0);
                acc1 = __builtin_amdgcn_mfma_f32_16x16x32_bf16(a, wfrag[kt][1], acc1, 0, 0, 0);
            }
            // Epilogue: D[m'][n] at col=l&15, row=4*g+r (m89-verified).
            float pz[4];
            #pragma unroll
            for (int r = 0; r < 4; ++r)
                pz[r] = fast_tanh(acc0[r] + b1a) * w2a + fast_tanh(acc1[r] + b1b) * w2b;
            #pragma unroll
            for (int s = 1; s < 16; s <<= 1) {
                pz[0] += __shfl_xor(pz[0], s, 64);
                pz[1] += __shfl_xor(pz[1], s, 64);
                pz[2] += __shfl_xor(pz[2], s, 64);
                pz[3] += __shfl_xor(pz[3], s, 64);
            }
            if (col == 0) {
                #pragma unroll
                for (int r = 0; r < 4; ++r)
                    Zp[nh][mt * 16 + 4 * g + r] = pz[r];
            }
        }
        __syncthreads();   // bar: Zp ready

        // ---- wave0 cluster: softmax + o_new + M update ----
        if (tid < DIM) {
            float mx = -1e30f;
            #pragma unroll
            for (int m = 0; m < MEM; ++m) mx = fmaxf(mx, Zp[0][m] + Zp[1][m]);
            float s = 0.f, accn = 0.f;
            #pragma unroll
            for (int m = 0; m < MEM; ++m) {
                const float e = __expf(Zp[0][m] + Zp[1][m] - mx);
                s += e;
                accn = fmaf(tbase[m * DIM + tid], e, accn);
            }
            const float onew = accn / s;
            onew_sm[tid] = onew;   // wave-internal RAW: lockstep, no barrier

            const float* __restrict__ Wm = Wmem_w + (size_t)(hop * DIM + tid) * 192;
            float acc2 = Wmem_b[hop * DIM + tid];
            #pragma unroll
            for (int k = 0; k < 16; ++k) {
                const float4 w = *reinterpret_cast<const float4*>(Wm + 4 * k);
                acc2 += w.x * M_sm[4*k] + w.y * M_sm[4*k+1] + w.z * M_sm[4*k+2] + w.w * M_sm[4*k+3];
            }
            #pragma unroll
            for (int k = 0; k < 16; ++k) {
                const float4 w = *reinterpret_cast<const float4*>(Wm + 64 + 4 * k);
                acc2 += w.x * onew_sm[4*k] + w.y * onew_sm[4*k+1] + w.z * onew_sm[4*k+2] + w.w * onew_sm[4*k+3];
            }
            #pragma unroll
            for (int k = 0; k < 16; ++k) {
                const float4 w = *reinterpret_cast<const float4*>(Wm + 128 + 4 * k);
                acc2 += w.x * o_sm[4*k] + w.y * o_sm[4*k+1] + w.z * o_sm[4*k+2] + w.w * o_sm[4*k+3];
            }
            M_sm[tid] = fmaxf(acc2, 0.f);
            o_sm[tid] = onew;
        }
        __syncthreads();   // M/o (+Zp reuse) visible for next P2
    }

    // ---- Final (wave0 only) ----
    if (tid < DIM) {
        const float* __restrict__ zr = z_w + (size_t)tid * 128;
        float u = z_b[tid];
        #pragma unroll
        for (int k = 0; k < 16; ++k) {
            const float4 w = *reinterpret_cast<const float4*>(zr + 4 * k);
            u += w.x * M_sm[4*k] + w.y * M_sm[4*k+1] + w.z * M_sm[4*k+2] + w.w * M_sm[4*k+3];
        }
        #pragma unroll
        for (int k = 0; k < 16; ++k) {
            const float4 w = *reinterpret_cast<const float4*>(zr + 64 + 4 * k);
            u += w.x * vs_sm[4*k] + w.y * vs_sm[4*k+1] + w.z * vs_sm[4*k+2] + w.w * vs_sm[4*k+3];
        }
        float r = vs_sm[tid] * u;
        #pragma unroll
        for (int s = 1; s < 64; s <<= 1) r += __shfl_xor(r, s, 64);
        if (tid == 0) out[b] = r;
    }
}

extern "C" void kernel_launch(void* const* d_in, const int* in_sizes, int n_in,
                              void* d_out, int out_size, void* d_ws, size_t ws_size,
                              hipStream_t stream)
{
    const float* hs     = (const float*)d_in[0];
    const float* Rs     = (const float*)d_in[1];
    const float* ts     = (const float*)d_in[2];
    const float* vs     = (const float*)d_in[3];
    const float* W1_w   = (const float*)d_in[4];
    const float* W1_b   = (const float*)d_in[5];
    const float* W2_w   = (const float*)d_in[6];
    const float* Wmem_w = (const float*)d_in[8];
    const float* Wmem_b = (const float*)d_in[9];
    const float* z_w    = (const float*)d_in[10];
    const float* z_b    = (const float*)d_in[11];
    float* out = (float*)d_out;
    float* rh  = (float*)d_ws;                 // B*2*32*64 floats = 16 MB

    const int B = out_size;                    // 1024
    const int gridA = B * NHOP * MEM / 16;     // 16 matvecs per block -> 4096
    rh_stream<<<gridA, 256, 0, stream>>>(Rs, hs, rh);
    ripple_chain<<<B, 256, 0, stream>>>(rh, ts, vs, W1_w, W1_b, (const float*)d_in[6],
                                        Wmem_w, Wmem_b, z_w, z_b, out);
    (void)W1_w; (void)ws_size; (void)n_in; (void)in_sizes;
}